// Round 2
// baseline (186.111 us; speedup 1.0000x reference)
//
#include <hip/hip_runtime.h>

#define BATCH 2048
#define NNODES 512
#define HID 64
#define LN_EPS 1e-5f
#define NEG_SLOPE 0.01f

#define ROWS_PER_BLOCK 128
#define NTHREADS 256
#define XPAD 4   // XsT row stride 132 floats (16B-aligned)
#define WPAD 4   // Ws  row stride 68 floats  (16B-aligned)

typedef __attribute__((ext_vector_type(4))) float f32x4;

// Exact-f32 path (bisect experiment): same sfac/bias/LN/leaky/indexing as the
// MFMA version, matmul via register-tiled VALU GEMM.
// Block = 1 node x 128 batch rows. 256 threads; thread tile = 8 rows x 4 cols.
__global__ __launch_bounds__(NTHREADS) void wv_f32_kernel(
    const float* __restrict__ x,      // [B, N, H]
    const float* __restrict__ dec,    // [3, 4]
    const float* __restrict__ rec,    // [3, 4]
    const float* __restrict__ W,      // [N, H, H]
    const float* __restrict__ bias,   // [N, H]
    const float* __restrict__ gamma,  // [N, H]
    const float* __restrict__ beta,   // [N, H]
    const int*   __restrict__ scales, // [N]
    float* __restrict__ out)          // [B, N, H]
{
    __shared__ float XsT[HID][ROWS_PER_BLOCK + XPAD]; // [k][row], sfac applied
    __shared__ float Ws [HID][HID + WPAD];            // [k][col] = W[n][col][k]

    const int tid   = threadIdx.x;
    const int node  = blockIdx.x >> 4;   // 512 nodes
    const int chunk = blockIdx.x & 15;   // 16 chunks of 128 rows
    const int b0    = chunk * ROWS_PER_BLOCK;

    const int   sc   = scales[node];
    const float sfac = dec[sc * 4 + 1] + rec[sc * 4 + 1];

    // ---- stage X^T with sfac applied: 128 rows x 64 h = 2048 quads, 8 iters
    #pragma unroll
    for (int it = 0; it < 8; ++it) {
        int q   = it * NTHREADS + tid;
        int row = q >> 4;           // 0..127
        int h4  = (q & 15) * 4;     // 0,4,...,60
        f32x4 v = *reinterpret_cast<const f32x4*>(
            x + ((size_t)(b0 + row) * NNODES + node) * HID + h4);
        XsT[h4 + 0][row] = v[0] * sfac;
        XsT[h4 + 1][row] = v[1] * sfac;
        XsT[h4 + 2][row] = v[2] * sfac;
        XsT[h4 + 3][row] = v[3] * sfac;
    }

    // ---- stage W transposed: Ws[k][col] = W[node][col][k]; 1024 quads, 4 iters
    const float* Wn = W + (size_t)node * HID * HID;
    #pragma unroll
    for (int it = 0; it < 4; ++it) {
        int q   = it * NTHREADS + tid;
        int col = q >> 4;           // 0..63
        int h4  = (q & 15) * 4;
        f32x4 v = *reinterpret_cast<const f32x4*>(Wn + col * HID + h4);
        Ws[h4 + 0][col] = v[0];
        Ws[h4 + 1][col] = v[1];
        Ws[h4 + 2][col] = v[2];
        Ws[h4 + 3][col] = v[3];
    }

    __syncthreads();

    const int rg = tid >> 4;   // 0..15 -> rows rg*8..+7
    const int cg = tid & 15;   // 0..15 -> cols cg*4..+3

    float acc[8][4];
    #pragma unroll
    for (int j = 0; j < 8; ++j)
        #pragma unroll
        for (int c = 0; c < 4; ++c) acc[j][c] = 0.f;

    #pragma unroll 8
    for (int k = 0; k < HID; ++k) {
        f32x4 a0 = *reinterpret_cast<const f32x4*>(&XsT[k][rg * 8]);
        f32x4 a1 = *reinterpret_cast<const f32x4*>(&XsT[k][rg * 8 + 4]);
        f32x4 bv = *reinterpret_cast<const f32x4*>(&Ws[k][cg * 4]);
        #pragma unroll
        for (int c = 0; c < 4; ++c) {
            acc[0][c] = fmaf(a0[0], bv[c], acc[0][c]);
            acc[1][c] = fmaf(a0[1], bv[c], acc[1][c]);
            acc[2][c] = fmaf(a0[2], bv[c], acc[2][c]);
            acc[3][c] = fmaf(a0[3], bv[c], acc[3][c]);
            acc[4][c] = fmaf(a1[0], bv[c], acc[4][c]);
            acc[5][c] = fmaf(a1[1], bv[c], acc[5][c]);
            acc[6][c] = fmaf(a1[2], bv[c], acc[6][c]);
            acc[7][c] = fmaf(a1[3], bv[c], acc[7][c]);
        }
    }

    // ---- epilogue: +bias, two-pass LayerNorm over 64 cols, leaky relu
    const int pbase = node * HID + cg * 4;
    f32x4 bb = *reinterpret_cast<const f32x4*>(bias  + pbase);
    f32x4 gg = *reinterpret_cast<const f32x4*>(gamma + pbase);
    f32x4 be = *reinterpret_cast<const f32x4*>(beta  + pbase);

    #pragma unroll
    for (int j = 0; j < 8; ++j) {
        float t0 = acc[j][0] + bb[0];
        float t1 = acc[j][1] + bb[1];
        float t2 = acc[j][2] + bb[2];
        float t3 = acc[j][3] + bb[3];
        float pS = t0 + t1 + t2 + t3;
        #pragma unroll
        for (int m = 1; m < 16; m <<= 1) pS += __shfl_xor(pS, m, 64);
        const float mu = pS * (1.0f / 64.0f);

        float d0 = t0 - mu, d1 = t1 - mu, d2 = t2 - mu, d3 = t3 - mu;
        float qS = d0 * d0 + d1 * d1 + d2 * d2 + d3 * d3;
        #pragma unroll
        for (int m = 1; m < 16; m <<= 1) qS += __shfl_xor(qS, m, 64);
        const float var  = qS * (1.0f / 64.0f);
        const float rstd = 1.0f / sqrtf(var + LN_EPS);

        f32x4 o;
        o[0] = d0 * rstd * gg[0] + be[0];
        o[1] = d1 * rstd * gg[1] + be[1];
        o[2] = d2 * rstd * gg[2] + be[2];
        o[3] = d3 * rstd * gg[3] + be[3];
        #pragma unroll
        for (int c = 0; c < 4; ++c) o[c] = o[c] >= 0.f ? o[c] : o[c] * NEG_SLOPE;

        const int row = b0 + rg * 8 + j;
        *reinterpret_cast<f32x4*>(
            out + ((size_t)row * NNODES + node) * HID + cg * 4) = o;
    }
}

extern "C" void kernel_launch(void* const* d_in, const int* in_sizes, int n_in,
                              void* d_out, int out_size, void* d_ws, size_t ws_size,
                              hipStream_t stream) {
    const float* x      = (const float*)d_in[0];
    const float* dec    = (const float*)d_in[1];
    const float* rec    = (const float*)d_in[2];
    const float* W      = (const float*)d_in[3];
    const float* bias   = (const float*)d_in[4];
    const float* gamma  = (const float*)d_in[5];
    const float* beta   = (const float*)d_in[6];
    const int*   scales = (const int*)d_in[7];
    float* out = (float*)d_out;

    const int blocks = NNODES * (BATCH / ROWS_PER_BLOCK);  // 512*16 = 8192
    wv_f32_kernel<<<blocks, NTHREADS, 0, stream>>>(
        x, dec, rec, W, bias, gamma, beta, scales, out);
}

// Round 3
// 145.530 us; speedup vs baseline: 1.2788x; 1.2788x over previous
//
#include <hip/hip_runtime.h>
#include <hip/hip_bf16.h>

#define BATCH 2048
#define NNODES 512
#define HID 64
#define LN_EPS 1e-5f
#define NEG_SLOPE 0.01f

#define ROWS 128      // batch rows per block
#define NTHREADS 256  // 4 waves
#define TPAD 4        // tLds row stride 68 f32 (272B, 16B-aligned)

typedef __attribute__((ext_vector_type(8))) short bf16x8;
typedef __attribute__((ext_vector_type(4))) float f32x4;

__device__ __forceinline__ short f2bf(float f) {
    union { __hip_bfloat16 h; short s; } u;
    u.h = __float2bfloat16(f);   // canonical RNE conversion
    return u.s;
}

// Block = 1 node x 128 batch rows, 256 threads (4 waves).
// Matmul: MFMA 16x16x32 bf16, fragments loaded directly from global.
// acc -> tLds (f32) at C-layout {col=lane&15, row=(lane>>4)*4+reg},
// then the round-2-verified epilogue (bias + two-pass LN + leaky) verbatim.
__global__ __launch_bounds__(NTHREADS) void wv_mfma_kernel(
    const float* __restrict__ x,      // [B, N, H]
    const float* __restrict__ dec,    // [3, 4]
    const float* __restrict__ rec,    // [3, 4]
    const float* __restrict__ W,      // [N, H, H]
    const float* __restrict__ bias,   // [N, H]
    const float* __restrict__ gamma,  // [N, H]
    const float* __restrict__ beta,   // [N, H]
    const int*   __restrict__ scales, // [N]
    float* __restrict__ out)          // [B, N, H]
{
    __shared__ float tLds[ROWS][HID + TPAD];   // 34816 B

    const int tid  = threadIdx.x;
    const int wave = tid >> 6;
    const int lane = tid & 63;
    const int l16  = lane & 15;
    const int lg   = lane >> 4;      // 0..3

    const int node  = blockIdx.x >> 4;   // 0..511
    const int chunk = blockIdx.x & 15;   // 0..15
    const int b0    = chunk * ROWS;

    const int   sc   = scales[node];
    const float sfac = dec[sc * 4 + 1] + rec[sc * 4 + 1];

    // ---- B fragments: lane holds W[node][c*16+l16][s*32 + lg*8 + j]
    bf16x8 wf[4][2];
    const float* Wn = W + (size_t)node * HID * HID;
    #pragma unroll
    for (int c = 0; c < 4; ++c) {
        #pragma unroll
        for (int s = 0; s < 2; ++s) {
            const float* p = Wn + (c * 16 + l16) * HID + s * 32 + lg * 8;
            f32x4 w0 = *reinterpret_cast<const f32x4*>(p);
            f32x4 w1 = *reinterpret_cast<const f32x4*>(p + 4);
            bf16x8 f;
            f[0] = f2bf(w0[0]); f[1] = f2bf(w0[1]); f[2] = f2bf(w0[2]); f[3] = f2bf(w0[3]);
            f[4] = f2bf(w1[0]); f[5] = f2bf(w1[1]); f[6] = f2bf(w1[2]); f[7] = f2bf(w1[3]);
            wf[c][s] = f;
        }
    }

    // ---- each wave: 32 rows as two 16-row MFMA tiles
    #pragma unroll
    for (int sub = 0; sub < 2; ++sub) {
        const int rl = wave * 32 + sub * 16;   // local row base

        bf16x8 af[2];
        #pragma unroll
        for (int s = 0; s < 2; ++s) {
            const float* p = x + ((size_t)(b0 + rl + l16) * NNODES + node) * HID + s * 32 + lg * 8;
            f32x4 x0 = *reinterpret_cast<const f32x4*>(p);
            f32x4 x1 = *reinterpret_cast<const f32x4*>(p + 4);
            bf16x8 f;
            f[0] = f2bf(x0[0] * sfac); f[1] = f2bf(x0[1] * sfac);
            f[2] = f2bf(x0[2] * sfac); f[3] = f2bf(x0[3] * sfac);
            f[4] = f2bf(x1[0] * sfac); f[5] = f2bf(x1[1] * sfac);
            f[6] = f2bf(x1[2] * sfac); f[7] = f2bf(x1[3] * sfac);
            af[s] = f;
        }

        f32x4 acc[4];
        #pragma unroll
        for (int c = 0; c < 4; ++c) {
            acc[c][0] = 0.f; acc[c][1] = 0.f; acc[c][2] = 0.f; acc[c][3] = 0.f;
            acc[c] = __builtin_amdgcn_mfma_f32_16x16x32_bf16(af[0], wf[c][0], acc[c], 0, 0, 0);
            acc[c] = __builtin_amdgcn_mfma_f32_16x16x32_bf16(af[1], wf[c][1], acc[c], 0, 0, 0);
        }

        // ---- spill t to LDS at the assumed C/D layout
        #pragma unroll
        for (int c = 0; c < 4; ++c)
            #pragma unroll
            for (int i = 0; i < 4; ++i)
                tLds[rl + lg * 4 + i][c * 16 + l16] = acc[c][i];
    }

    __syncthreads();

    // ---- round-2-verified epilogue, verbatim (reads tLds instead of acc)
    const int rg = tid >> 4;   // 0..15 -> rows rg*8..+7
    const int cg = tid & 15;   // 0..15 -> cols cg*4..+3

    const int pbase = node * HID + cg * 4;
    f32x4 bb = *reinterpret_cast<const f32x4*>(bias  + pbase);
    f32x4 gg = *reinterpret_cast<const f32x4*>(gamma + pbase);
    f32x4 be = *reinterpret_cast<const f32x4*>(beta  + pbase);

    #pragma unroll
    for (int j = 0; j < 8; ++j) {
        f32x4 tv = *reinterpret_cast<const f32x4*>(&tLds[rg * 8 + j][cg * 4]);
        float t0 = tv[0] + bb[0];
        float t1 = tv[1] + bb[1];
        float t2 = tv[2] + bb[2];
        float t3 = tv[3] + bb[3];
        float pS = t0 + t1 + t2 + t3;
        #pragma unroll
        for (int m = 1; m < 16; m <<= 1) pS += __shfl_xor(pS, m, 64);
        const float mu = pS * (1.0f / 64.0f);

        float d0 = t0 - mu, d1 = t1 - mu, d2 = t2 - mu, d3 = t3 - mu;
        float qS = d0 * d0 + d1 * d1 + d2 * d2 + d3 * d3;
        #pragma unroll
        for (int m = 1; m < 16; m <<= 1) qS += __shfl_xor(qS, m, 64);
        const float var  = qS * (1.0f / 64.0f);
        const float rstd = 1.0f / sqrtf(var + LN_EPS);

        f32x4 o;
        o[0] = d0 * rstd * gg[0] + be[0];
        o[1] = d1 * rstd * gg[1] + be[1];
        o[2] = d2 * rstd * gg[2] + be[2];
        o[3] = d3 * rstd * gg[3] + be[3];
        #pragma unroll
        for (int c = 0; c < 4; ++c) o[c] = o[c] >= 0.f ? o[c] : o[c] * NEG_SLOPE;

        const int row = b0 + rg * 8 + j;
        *reinterpret_cast<f32x4*>(
            out + ((size_t)row * NNODES + node) * HID + cg * 4) = o;
    }
}

extern "C" void kernel_launch(void* const* d_in, const int* in_sizes, int n_in,
                              void* d_out, int out_size, void* d_ws, size_t ws_size,
                              hipStream_t stream) {
    const float* x      = (const float*)d_in[0];
    const float* dec    = (const float*)d_in[1];
    const float* rec    = (const float*)d_in[2];
    const float* W      = (const float*)d_in[3];
    const float* bias   = (const float*)d_in[4];
    const float* gamma  = (const float*)d_in[5];
    const float* beta   = (const float*)d_in[6];
    const int*   scales = (const int*)d_in[7];
    float* out = (float*)d_out;

    const int blocks = NNODES * (BATCH / ROWS);  // 8192
    wv_mfma_kernel<<<blocks, NTHREADS, 0, stream>>>(
        x, dec, rec, W, bias, gamma, beta, scales, out);
}